// Round 6
// baseline (378.097 us; speedup 1.0000x reference)
//
#include <hip/hip_runtime.h>
#include <hip/hip_bf16.h>

#define DIM 128

typedef __bf16 bf16x8 __attribute__((ext_vector_type(8)));
typedef float f32x4 __attribute__((ext_vector_type(4)));

static inline int cdiv(int a, int b) { return (a + b - 1) / b; }
static inline size_t align256(size_t x) { return (x + 255) & ~size_t(255); }

__device__ inline unsigned short f2bf(float f) {
    union { float f; unsigned int u; } v; v.f = f;
    unsigned int r = v.u + 0x7fff + ((v.u >> 16) & 1);   // RNE
    return (unsigned short)(r >> 16);
}
__device__ inline unsigned int hb(float f) {             // half-up bf16, 2 ops
    return (__builtin_bit_cast(unsigned int, f) + 0x8000u) >> 16;
}

// -------- setup (merged): segment offsets (both tables) + fp32->bf16 convert
// + W swizzle, one launch. Jobs dispatched by global thread id range.
__global__ void setup_all_kernel(const int* __restrict__ segA, int mA, int nA,
                                 int* __restrict__ offA,
                                 const int* __restrict__ segB, int mB, int nB,
                                 int* __restrict__ offB,
                                 const float* __restrict__ xin,
                                 unsigned short* __restrict__ xout, int n4,
                                 const float* __restrict__ W_e,
                                 const float* __restrict__ W_n,
                                 unsigned short* __restrict__ wsw) {
    int gid = blockIdx.x * blockDim.x + threadIdx.x;

    // job B: fp32 -> bf16 convert (bulk of the work, n4 = N*DIM/4 threads)
    if (gid < n4) {
        float4 v = ((const float4*)xin)[gid];
        ushort4 o;
        o.x = f2bf(v.x); o.y = f2bf(v.y); o.z = f2bf(v.z); o.w = f2bf(v.w);
        ((ushort4*)xout)[gid] = o;
    }

    // job A: segment-offset tables via binary search
    if (gid <= nA) {
        int lo = 0, hi = mA;
        while (lo < hi) { int mid = (lo + hi) >> 1; if (segA[mid] < gid) lo = mid + 1; else hi = mid; }
        offA[gid] = lo;
    }
    int jj = gid - (nA + 1);
    if (jj >= 0 && jj <= nB) {
        int lo = 0, hi = mB;
        while (lo < hi) { int mid = (lo + hi) >> 1; if (segB[mid] < jj) lo = mid + 1; else hi = mid; }
        offB[jj] = lo;
    }

    // job C: pre-swizzle W (4 matrices of 128x128 fp32) into frag-major bf16
    if (gid < 8192) {
        int mi = gid >> 11;
        int e = gid & 2047;
        const float* W = (mi < 2) ? (W_e + (size_t)mi * DIM * DIM)
                                  : (W_n + (size_t)(mi - 2) * DIM * DIM);
        int t = e >> 9, n = (e >> 6) & 7, lane = e & 63;
        int q = lane >> 4, c = lane & 15;
        int k0 = t * 32 + q * 8, col = n * 16 + c;
        unsigned short vals[8];
#pragma unroll
        for (int j = 0; j < 8; ++j) vals[j] = f2bf(W[(size_t)(k0 + j) * DIM + col]);
        ushort4* dst = (ushort4*)(wsw + (size_t)gid * 8);
        dst[0] = make_ushort4(vals[0], vals[1], vals[2], vals[3]);
        dst[1] = make_ushort4(vals[4], vals[5], vals[6], vals[7]);
    }
}

// weighted accumulate: 3 VALU/uint (hi = direct bitcast; validated since v7)
__device__ inline void accum8s(float* a, uint4 v, float wt) {
    unsigned int u[4] = {v.x, v.y, v.z, v.w};
#pragma unroll
    for (int i = 0; i < 4; ++i) {
        a[2 * i]     = fmaf(wt, __builtin_bit_cast(float, u[i] << 16), a[2 * i]);
        a[2 * i + 1] = fmaf(wt, __builtin_bit_cast(float, u[i]),       a[2 * i + 1]);
    }
}

// -------- kernel 4 v12: FUSED pool + GEMM + LN + ReLU.
// Structure = v7 (W staged in LDS, XOR-swizzled 32KB A-tile, single barrier,
// 512 thr) with the pooling loop deepened to 8 MEMBERS IN FLIGHT.
// Model from R1-R5: every MLP-4 variant lands at 55-65us regardless of
// geometry (dur ~ volume x latency / (waves x in-flight)); the chunk-per-lane
// accumulator (8 f32) is what makes depth-8 affordable under the 64-VGPR
// cliff (R3: full-row acc + depth-2 = 68 VGPR = cliff; here 32 load regs +
// 8 acc ~= 55 live).
__global__ __launch_bounds__(512)
void fused_pool_gemm_ln_relu_v12_kernel(const uint4* __restrict__ src,
                                        const int* __restrict__ map,
                                        const int* __restrict__ off,
                                        const unsigned short* __restrict__ Wsw,
                                        const float* __restrict__ b,
                                        const float* __restrict__ g,
                                        const float* __restrict__ be,
                                        unsigned short* __restrict__ Y,
                                        int nseg) {
    __shared__ bf16x8 wlds[2048];              // 32 KB, frag-major W
    __shared__ unsigned short alds[128 * 128]; // 32 KB pooled A-tile, XOR-swizzled
    int tid = threadIdx.x;
    int w = tid >> 6, lane = tid & 63;
    int q = lane >> 4, c = lane & 15;

    {   // stage swizzled W (global layout == LDS layout)
        const uint4* gsrc = (const uint4*)Wsw;
        uint4* ldst = (uint4*)wlds;
#pragma unroll
        for (int i = 0; i < 4; ++i) ldst[tid + i * 512] = gsrc[tid + i * 512];
    }

    int blockbase = blockIdx.x * 128;
    int wavebase = w * 16;

    // segment bounds for the 4 pooling rounds (early independent loads)
    int begv[4], endv[4];
#pragma unroll
    for (int it = 0; it < 4; ++it) {
        int sc = min(blockbase + wavebase + it * 4 + q, nseg - 1);
        begv[it] = off[sc];
        endv[it] = off[sc + 1];
    }

    __syncthreads();   // only barrier: W visible to all waves

    // ---- phase 1: wave pools its own 16 rows; round it pools segment
    // wavebase+it*4+q with 16 c-lanes covering the 256B row (coalesced).
    // 8 members in flight; next batch's indices prefetched alongside.
    const char* sbase = (const char*)src;
    unsigned cb = (unsigned)(c << 4);   // lane's byte offset within a row
    for (int it = 0; it < 4; ++it) {
        int s_local = wavebase + it * 4 + q;
        int beg = begv[it], end = endv[it];
        int e1 = max(end - 1, 0);
        float a[8] = {0.f, 0.f, 0.f, 0.f, 0.f, 0.f, 0.f, 0.f};
        unsigned r0 = (unsigned)map[min(beg,     e1)];
        unsigned r1 = (unsigned)map[min(beg + 1, e1)];
        unsigned r2 = (unsigned)map[min(beg + 2, e1)];
        unsigned r3 = (unsigned)map[min(beg + 3, e1)];
        unsigned r4 = (unsigned)map[min(beg + 4, e1)];
        unsigned r5 = (unsigned)map[min(beg + 5, e1)];
        unsigned r6 = (unsigned)map[min(beg + 6, e1)];
        unsigned r7 = (unsigned)map[min(beg + 7, e1)];
        for (int j = beg; j < end; j += 8) {
            uint4 v0 = *(const uint4*)(sbase + ((r0 << 8) + cb));
            uint4 v1 = *(const uint4*)(sbase + ((r1 << 8) + cb));
            uint4 v2 = *(const uint4*)(sbase + ((r2 << 8) + cb));
            uint4 v3 = *(const uint4*)(sbase + ((r3 << 8) + cb));
            uint4 v4 = *(const uint4*)(sbase + ((r4 << 8) + cb));
            uint4 v5 = *(const uint4*)(sbase + ((r5 << 8) + cb));
            uint4 v6 = *(const uint4*)(sbase + ((r6 << 8) + cb));
            uint4 v7 = *(const uint4*)(sbase + ((r7 << 8) + cb));
            int jn = j + 8;
            unsigned t0 = (unsigned)map[min(jn,     e1)];   // prefetch next batch
            unsigned t1 = (unsigned)map[min(jn + 1, e1)];
            unsigned t2 = (unsigned)map[min(jn + 2, e1)];
            unsigned t3 = (unsigned)map[min(jn + 3, e1)];
            unsigned t4 = (unsigned)map[min(jn + 4, e1)];
            unsigned t5 = (unsigned)map[min(jn + 5, e1)];
            unsigned t6 = (unsigned)map[min(jn + 6, e1)];
            unsigned t7 = (unsigned)map[min(jn + 7, e1)];
            accum8s(a, v0, 1.f);
            accum8s(a, v1, (j + 1 < end) ? 1.f : 0.f);
            accum8s(a, v2, (j + 2 < end) ? 1.f : 0.f);
            accum8s(a, v3, (j + 3 < end) ? 1.f : 0.f);
            accum8s(a, v4, (j + 4 < end) ? 1.f : 0.f);
            accum8s(a, v5, (j + 5 < end) ? 1.f : 0.f);
            accum8s(a, v6, (j + 6 < end) ? 1.f : 0.f);
            accum8s(a, v7, (j + 7 < end) ? 1.f : 0.f);
            r0 = t0; r1 = t1; r2 = t2; r3 = t3;
            r4 = t4; r5 = t5; r6 = t6; r7 = t7;
        }
        float inv = 1.f / fmaxf((float)(end - beg), 1.f);
        uint4 o;
        o.x = hb(a[0] * inv) | (hb(a[1] * inv) << 16);
        o.y = hb(a[2] * inv) | (hb(a[3] * inv) << 16);
        o.z = hb(a[4] * inv) | (hb(a[5] * inv) << 16);
        o.w = hb(a[6] * inv) | (hb(a[7] * inv) << 16);
        uint4* wrow = (uint4*)(alds + (size_t)s_local * 128);
        wrow[c ^ (s_local & 7)] = o;    // XOR-swizzled store
    }

    // bias (seeds acc); g/be deferred past MFMA to cap pressure
    float bcol[8];
#pragma unroll
    for (int n = 0; n < 8; ++n) bcol[n] = b[n * 16 + c];

    f32x4 acc[8];
#pragma unroll
    for (int n = 0; n < 8; ++n) acc[n] = f32x4{bcol[n], bcol[n], bcol[n], bcol[n]};

    // ---- phase 2: GEMM from own LDS rows (wave-local ds ordering; no barrier)
    const uint4* arow = (const uint4*)(alds + (size_t)(wavebase + c) * 128);
    int key = c & 7;
    bf16x8 a0 = *(const bf16x8*)&arow[(q + 0) ^ key];
    bf16x8 a1 = *(const bf16x8*)&arow[(q + 4) ^ key];
    bf16x8 a2 = *(const bf16x8*)&arow[(q + 8) ^ key];
    bf16x8 a3 = *(const bf16x8*)&arow[(q + 12) ^ key];

#pragma unroll
    for (int n = 0; n < 8; ++n) {
        acc[n] = __builtin_amdgcn_mfma_f32_16x16x32_bf16(a0, wlds[(0 * 8 + n) * 64 + lane], acc[n], 0, 0, 0);
        acc[n] = __builtin_amdgcn_mfma_f32_16x16x32_bf16(a1, wlds[(1 * 8 + n) * 64 + lane], acc[n], 0, 0, 0);
        acc[n] = __builtin_amdgcn_mfma_f32_16x16x32_bf16(a2, wlds[(2 * 8 + n) * 64 + lane], acc[n], 0, 0, 0);
        acc[n] = __builtin_amdgcn_mfma_f32_16x16x32_bf16(a3, wlds[(3 * 8 + n) * 64 + lane], acc[n], 0, 0, 0);
    }

    // LN sums per row (lane's rows: blockbase + w*16 + q*4 + j, col n*16+c)
    float s1[4], s2[4];
#pragma unroll
    for (int j = 0; j < 4; ++j) {
        float t1 = 0.f, t2 = 0.f;
#pragma unroll
        for (int n = 0; n < 8; ++n) { float v = acc[n][j]; t1 += v; t2 = fmaf(v, v, t2); }
        s1[j] = t1; s2[j] = t2;
    }
#pragma unroll
    for (int o = 1; o < 16; o <<= 1)
#pragma unroll
        for (int j = 0; j < 4; ++j) {
            s1[j] += __shfl_xor(s1[j], o);
            s2[j] += __shfl_xor(s2[j], o);
        }

    float gcol[8], becol[8];
#pragma unroll
    for (int n = 0; n < 8; ++n) {
        int col = n * 16 + c;
        gcol[n] = g[col]; becol[n] = be[col];
    }

#pragma unroll
    for (int j = 0; j < 4; ++j) {
        int row = blockbase + w * 16 + q * 4 + j;
        if (row >= nseg) continue;
        float m = s1[j] * (1.f / DIM);
        float var = fmaf(-m, m, s2[j] * (1.f / DIM));
        float invs = rsqrtf(var + 1e-5f);
        unsigned short* yp = Y + (size_t)row * DIM + c;
#pragma unroll
        for (int n = 0; n < 8; ++n) {
            float d = acc[n][j] - m;
            float y = fmaxf(fmaf(d * invs, gcol[n], becol[n]), 0.f);
            unsigned int u = __builtin_bit_cast(unsigned int, y) + 0x8000u;  // half-up
            yp[n * 16] = (unsigned short)(u >> 16);   // -> global_store_short_d16_hi
        }
    }
}

// -------- kernel 5: classifier + log_softmax, quarter-wave per row, 4 rows/quarter.
#define CL_ROWS 4
__global__ __launch_bounds__(256)
void classifier_logsoftmax_v3_kernel(const uint4* __restrict__ X,
                                     const float* __restrict__ Wc,
                                     const float* __restrict__ bc,
                                     float* __restrict__ out, int nrows) {
    int w = threadIdx.x >> 6, lane = threadIdx.x & 63;
    int g = lane >> 4, c16 = lane & 15;
    int r0 = (blockIdx.x * 16 + w * 4 + g) * CL_ROWS;
    if (r0 >= nrows) return;

    float wc[8][10];
#pragma unroll
    for (int j = 0; j < 8; ++j)
#pragma unroll
        for (int c = 0; c < 10; ++c) wc[j][c] = Wc[(c16 * 8 + j) * 10 + c];
    float bcv[10];
#pragma unroll
    for (int c = 0; c < 10; ++c) bcv[c] = bc[c];

    int rend = min(r0 + CL_ROWS, nrows);
    for (int r = r0; r < rend; ++r) {
        uint4 v = X[(size_t)r * 16 + c16];
        float x[8];
        {
            unsigned int u[4] = {v.x, v.y, v.z, v.w};
#pragma unroll
            for (int i = 0; i < 4; ++i) {
                union { unsigned int ui; float f; } lo, hi;
                lo.ui = u[i] << 16;
                hi.ui = u[i] & 0xffff0000u;
                x[2 * i] = lo.f; x[2 * i + 1] = hi.f;
            }
        }
        float acc[10];
#pragma unroll
        for (int c = 0; c < 10; ++c) acc[c] = 0.f;
#pragma unroll
        for (int j = 0; j < 8; ++j)
#pragma unroll
            for (int c = 0; c < 10; ++c) acc[c] = fmaf(x[j], wc[j][c], acc[c]);

#pragma unroll
        for (int o = 1; o < 16; o <<= 1)
#pragma unroll
            for (int c = 0; c < 10; ++c) acc[c] += __shfl_xor(acc[c], o);

#pragma unroll
        for (int c = 0; c < 10; ++c) acc[c] += bcv[c];

        float mx = acc[0];
#pragma unroll
        for (int c = 1; c < 10; ++c) mx = fmaxf(mx, acc[c]);
        float se = 0.f;
#pragma unroll
        for (int c = 0; c < 10; ++c) se += expf(acc[c] - mx);
        float lse = mx + logf(se);

        float myv = 0.f;
#pragma unroll
        for (int c = 0; c < 10; ++c) myv = (c16 == c) ? acc[c] : myv;
        if (c16 < 10) out[(size_t)r * 10 + c16] = myv - lse;
    }
}

extern "C" void kernel_launch(void* const* d_in, const int* in_sizes, int n_in,
                              void* d_out, int out_size, void* d_ws, size_t ws_size,
                              hipStream_t stream) {
    const float* node_x    = (const float*)d_in[0];
    const int*   nodes_map = (const int*)d_in[1];
    const int*   edge_seg  = (const int*)d_in[2];
    const int*   edges_map = (const int*)d_in[3];
    const int*   node_seg  = (const int*)d_in[4];
    const float* W_e = (const float*)d_in[6];
    const float* b_e = (const float*)d_in[7];
    const float* g_e = (const float*)d_in[8];
    const float* be_e= (const float*)d_in[9];
    const float* W_n = (const float*)d_in[10];
    const float* b_n = (const float*)d_in[11];
    const float* g_n = (const float*)d_in[12];
    const float* be_n= (const float*)d_in[13];
    const float* W_c = (const float*)d_in[14];
    const float* b_c = (const float*)d_in[15];
    float* out = (float*)d_out;

    const int N = in_sizes[0] / DIM;           // 100000
    const int M = in_sizes[1];                 // 800000
    const int E = 200000;                      // N_EDGES (problem constant)
    const int L = in_sizes[6] / (DIM * DIM);   // 2

    // workspace carve-up
    char* ws = (char*)d_ws;
    int* edge_off = (int*)ws;           ws += align256((size_t)(E + 1) * sizeof(int));
    int* node_off = (int*)ws;           ws += align256((size_t)(N + 1) * sizeof(int));
    unsigned short* wsw = (unsigned short*)ws;      ws += align256((size_t)4 * 2048 * 8 * sizeof(unsigned short));
    unsigned short* node_xb = (unsigned short*)ws;  ws += align256((size_t)N * DIM * sizeof(unsigned short));
    unsigned short* exb = (unsigned short*)ws;      ws += align256((size_t)E * DIM * sizeof(unsigned short));
    unsigned short* xb  = (unsigned short*)ws;      ws += align256((size_t)N * DIM * sizeof(unsigned short));
    (void)ws_size;

    setup_all_kernel<<<cdiv(N * DIM / 4, 256), 256, 0, stream>>>(
        edge_seg, M, E, edge_off, node_seg, M, N, node_off,
        node_x, node_xb, N * DIM / 4, W_e, W_n, wsw);

    const unsigned short* xcur = node_xb;
    for (int i = 0; i < L; ++i) {
        // N2E: pool node rows per hyperedge, then edge-MLP
        fused_pool_gemm_ln_relu_v12_kernel<<<cdiv(E, 128), 512, 0, stream>>>(
            (const uint4*)xcur, nodes_map, edge_off, wsw + (size_t)i * 16384,
            b_e + i * DIM, g_e + i * DIM, be_e + i * DIM, exb, E);
        // E2N: pool edge rows per node, then node-MLP
        fused_pool_gemm_ln_relu_v12_kernel<<<cdiv(N, 128), 512, 0, stream>>>(
            (const uint4*)exb, edges_map, node_off, wsw + (size_t)(2 + i) * 16384,
            b_n + i * DIM, g_n + i * DIM, be_n + i * DIM, xb, N);
        xcur = xb;
    }

    classifier_logsoftmax_v3_kernel<<<cdiv(N, 16 * CL_ROWS), 256, 0, stream>>>(
        (const uint4*)xcur, W_c, b_c, out, N);
}

// Round 7
// 340.175 us; speedup vs baseline: 1.1115x; 1.1115x over previous
//
#include <hip/hip_runtime.h>
#include <hip/hip_bf16.h>

#define DIM 128

typedef __bf16 bf16x8 __attribute__((ext_vector_type(8)));
typedef float f32x4 __attribute__((ext_vector_type(4)));

static inline int cdiv(int a, int b) { return (a + b - 1) / b; }
static inline size_t align256(size_t x) { return (x + 255) & ~size_t(255); }

__device__ inline unsigned short f2bf(float f) {
    union { float f; unsigned int u; } v; v.f = f;
    unsigned int r = v.u + 0x7fff + ((v.u >> 16) & 1);   // RNE
    return (unsigned short)(r >> 16);
}
__device__ inline unsigned int hb(float f) {             // half-up bf16, 2 ops
    return (__builtin_bit_cast(unsigned int, f) + 0x8000u) >> 16;
}

// -------- setup (merged): segment offsets + fp32->bf16 convert + W swizzle
// + PADDED MAP COPIES (both maps, +16 zero entries) in one launch.
__global__ void setup_all_kernel(const int* __restrict__ segA, int mA, int nA,
                                 int* __restrict__ offA,
                                 const int* __restrict__ segB, int mB, int nB,
                                 int* __restrict__ offB,
                                 const float* __restrict__ xin,
                                 unsigned short* __restrict__ xout, int n4,
                                 const float* __restrict__ W_e,
                                 const float* __restrict__ W_n,
                                 unsigned short* __restrict__ wsw,
                                 const int* __restrict__ mapA,
                                 const int* __restrict__ mapB,
                                 int M,
                                 int* __restrict__ mapA_pad,
                                 int* __restrict__ mapB_pad) {
    int gid = blockIdx.x * blockDim.x + threadIdx.x;

    // job B: fp32 -> bf16 convert (bulk of the work, n4 = N*DIM/4 threads)
    if (gid < n4) {
        float4 v = ((const float4*)xin)[gid];
        ushort4 o;
        o.x = f2bf(v.x); o.y = f2bf(v.y); o.z = f2bf(v.z); o.w = f2bf(v.w);
        ((ushort4*)xout)[gid] = o;
    }

    // job D: padded map copies (removes per-batch index clamping in the
    // fused kernel's pooling loop — R6 post-mortem: those clamps + e1 regs
    // were part of the 4-register overshoot past the 64-VGPR cliff)
    if (gid < M + 16) {
        int vA = (gid < M) ? mapA[gid] : 0;
        int vB = (gid < M) ? mapB[gid] : 0;
        mapA_pad[gid] = vA;
        mapB_pad[gid] = vB;
    }

    // job A: segment-offset tables via binary search
    if (gid <= nA) {
        int lo = 0, hi = mA;
        while (lo < hi) { int mid = (lo + hi) >> 1; if (segA[mid] < gid) lo = mid + 1; else hi = mid; }
        offA[gid] = lo;
    }
    int jj = gid - (nA + 1);
    if (jj >= 0 && jj <= nB) {
        int lo = 0, hi = mB;
        while (lo < hi) { int mid = (lo + hi) >> 1; if (segB[mid] < jj) lo = mid + 1; else hi = mid; }
        offB[jj] = lo;
    }

    // job C: pre-swizzle W (4 matrices of 128x128 fp32) into frag-major bf16
    if (gid < 8192) {
        int mi = gid >> 11;
        int e = gid & 2047;
        const float* W = (mi < 2) ? (W_e + (size_t)mi * DIM * DIM)
                                  : (W_n + (size_t)(mi - 2) * DIM * DIM);
        int t = e >> 9, n = (e >> 6) & 7, lane = e & 63;
        int q = lane >> 4, c = lane & 15;
        int k0 = t * 32 + q * 8, col = n * 16 + c;
        unsigned short vals[8];
#pragma unroll
        for (int j = 0; j < 8; ++j) vals[j] = f2bf(W[(size_t)(k0 + j) * DIM + col]);
        ushort4* dst = (ushort4*)(wsw + (size_t)gid * 8);
        dst[0] = make_ushort4(vals[0], vals[1], vals[2], vals[3]);
        dst[1] = make_ushort4(vals[4], vals[5], vals[6], vals[7]);
    }
}

// weighted accumulate: 3 VALU/uint (hi = direct bitcast; validated since v7)
__device__ inline void accum8s(float* a, uint4 v, float wt) {
    unsigned int u[4] = {v.x, v.y, v.z, v.w};
#pragma unroll
    for (int i = 0; i < 4; ++i) {
        a[2 * i]     = fmaf(wt, __builtin_bit_cast(float, u[i] << 16), a[2 * i]);
        a[2 * i + 1] = fmaf(wt, __builtin_bit_cast(float, u[i]),       a[2 * i + 1]);
    }
}

// -------- kernel 4 v13: v12 (depth-8 chunk-geometry pooling, W in LDS,
// XOR-swizzled A-tile, single barrier) + REGISTER DIET to get under the
// 64-VGPR cliff: padded map (no e1/min clamps), endv de-hoisted (loaded
// per round; its consumers run after the row loads so latency hides).
// R6 datum: depth-8 per-wave throughput = 1.85x v8; it lost only because
// 68 VGPR crushed occupancy. This probe isolates VGPR 68 -> <=64.
__global__ __launch_bounds__(512)
void fused_pool_gemm_ln_relu_v13_kernel(const uint4* __restrict__ src,
                                        const int* __restrict__ map,   // padded +16
                                        const int* __restrict__ off,
                                        const unsigned short* __restrict__ Wsw,
                                        const float* __restrict__ b,
                                        const float* __restrict__ g,
                                        const float* __restrict__ be,
                                        unsigned short* __restrict__ Y,
                                        int nseg) {
    __shared__ bf16x8 wlds[2048];              // 32 KB, frag-major W
    __shared__ unsigned short alds[128 * 128]; // 32 KB pooled A-tile, XOR-swizzled
    int tid = threadIdx.x;
    int w = tid >> 6, lane = tid & 63;
    int q = lane >> 4, c = lane & 15;

    {   // stage swizzled W (global layout == LDS layout)
        const uint4* gsrc = (const uint4*)Wsw;
        uint4* ldst = (uint4*)wlds;
#pragma unroll
        for (int i = 0; i < 4; ++i) ldst[tid + i * 512] = gsrc[tid + i * 512];
    }

    int blockbase = blockIdx.x * 128;
    int wavebase = w * 16;
    int scb = blockbase + wavebase + q;   // + it*4 per round, clamped per use

    // hoist only beg (idx loads need it immediately); end loaded per round
    int begv[4];
#pragma unroll
    for (int it = 0; it < 4; ++it)
        begv[it] = off[min(scb + it * 4, nseg - 1)];

    __syncthreads();   // only barrier: W visible to all waves

    // ---- phase 1: round it pools segment wavebase+it*4+q; 16 c-lanes cover
    // the 256B row (coalesced); 8 members in flight, idx prefetched 1 batch
    // ahead (padded map: no clamping).
    const char* sbase = (const char*)src;
    unsigned cb = (unsigned)(c << 4);   // lane's byte offset within a row
#pragma unroll
    for (int it = 0; it < 4; ++it) {
        int s_local = wavebase + it * 4 + q;
        int beg = begv[it];
        int end = off[min(scb + it * 4, nseg - 1) + 1];  // latency hides under idx/row loads
        float a[8] = {0.f, 0.f, 0.f, 0.f, 0.f, 0.f, 0.f, 0.f};
        unsigned r0 = (unsigned)map[beg];
        unsigned r1 = (unsigned)map[beg + 1];
        unsigned r2 = (unsigned)map[beg + 2];
        unsigned r3 = (unsigned)map[beg + 3];
        unsigned r4 = (unsigned)map[beg + 4];
        unsigned r5 = (unsigned)map[beg + 5];
        unsigned r6 = (unsigned)map[beg + 6];
        unsigned r7 = (unsigned)map[beg + 7];
        for (int j = beg; j < end; j += 8) {
            uint4 v0 = *(const uint4*)(sbase + ((r0 << 8) + cb));
            uint4 v1 = *(const uint4*)(sbase + ((r1 << 8) + cb));
            uint4 v2 = *(const uint4*)(sbase + ((r2 << 8) + cb));
            uint4 v3 = *(const uint4*)(sbase + ((r3 << 8) + cb));
            uint4 v4 = *(const uint4*)(sbase + ((r4 << 8) + cb));
            uint4 v5 = *(const uint4*)(sbase + ((r5 << 8) + cb));
            uint4 v6 = *(const uint4*)(sbase + ((r6 << 8) + cb));
            uint4 v7 = *(const uint4*)(sbase + ((r7 << 8) + cb));
            int jn = j + 8;
            unsigned t0 = (unsigned)map[jn];       // prefetch next batch (padded)
            unsigned t1 = (unsigned)map[jn + 1];
            unsigned t2 = (unsigned)map[jn + 2];
            unsigned t3 = (unsigned)map[jn + 3];
            unsigned t4 = (unsigned)map[jn + 4];
            unsigned t5 = (unsigned)map[jn + 5];
            unsigned t6 = (unsigned)map[jn + 6];
            unsigned t7 = (unsigned)map[jn + 7];
            accum8s(a, v0, 1.f);
            accum8s(a, v1, (j + 1 < end) ? 1.f : 0.f);
            accum8s(a, v2, (j + 2 < end) ? 1.f : 0.f);
            accum8s(a, v3, (j + 3 < end) ? 1.f : 0.f);
            accum8s(a, v4, (j + 4 < end) ? 1.f : 0.f);
            accum8s(a, v5, (j + 5 < end) ? 1.f : 0.f);
            accum8s(a, v6, (j + 6 < end) ? 1.f : 0.f);
            accum8s(a, v7, (j + 7 < end) ? 1.f : 0.f);
            r0 = t0; r1 = t1; r2 = t2; r3 = t3;
            r4 = t4; r5 = t5; r6 = t6; r7 = t7;
        }
        float inv = 1.f / fmaxf((float)(end - beg), 1.f);
        uint4 o;
        o.x = hb(a[0] * inv) | (hb(a[1] * inv) << 16);
        o.y = hb(a[2] * inv) | (hb(a[3] * inv) << 16);
        o.z = hb(a[4] * inv) | (hb(a[5] * inv) << 16);
        o.w = hb(a[6] * inv) | (hb(a[7] * inv) << 16);
        uint4* wrow = (uint4*)(alds + (size_t)s_local * 128);
        wrow[c ^ (s_local & 7)] = o;    // XOR-swizzled store
    }

    // bias (seeds acc); g/be deferred past MFMA to cap pressure
    float bcol[8];
#pragma unroll
    for (int n = 0; n < 8; ++n) bcol[n] = b[n * 16 + c];

    f32x4 acc[8];
#pragma unroll
    for (int n = 0; n < 8; ++n) acc[n] = f32x4{bcol[n], bcol[n], bcol[n], bcol[n]};

    // ---- phase 2: GEMM from own LDS rows (wave-local ds ordering; no barrier)
    const uint4* arow = (const uint4*)(alds + (size_t)(wavebase + c) * 128);
    int key = c & 7;
    bf16x8 a0 = *(const bf16x8*)&arow[(q + 0) ^ key];
    bf16x8 a1 = *(const bf16x8*)&arow[(q + 4) ^ key];
    bf16x8 a2 = *(const bf16x8*)&arow[(q + 8) ^ key];
    bf16x8 a3 = *(const bf16x8*)&arow[(q + 12) ^ key];

#pragma unroll
    for (int n = 0; n < 8; ++n) {
        acc[n] = __builtin_amdgcn_mfma_f32_16x16x32_bf16(a0, wlds[(0 * 8 + n) * 64 + lane], acc[n], 0, 0, 0);
        acc[n] = __builtin_amdgcn_mfma_f32_16x16x32_bf16(a1, wlds[(1 * 8 + n) * 64 + lane], acc[n], 0, 0, 0);
        acc[n] = __builtin_amdgcn_mfma_f32_16x16x32_bf16(a2, wlds[(2 * 8 + n) * 64 + lane], acc[n], 0, 0, 0);
        acc[n] = __builtin_amdgcn_mfma_f32_16x16x32_bf16(a3, wlds[(3 * 8 + n) * 64 + lane], acc[n], 0, 0, 0);
    }

    // LN sums per row (lane's rows: blockbase + w*16 + q*4 + j, col n*16+c)
    float s1[4], s2[4];
#pragma unroll
    for (int j = 0; j < 4; ++j) {
        float t1 = 0.f, t2 = 0.f;
#pragma unroll
        for (int n = 0; n < 8; ++n) { float v = acc[n][j]; t1 += v; t2 = fmaf(v, v, t2); }
        s1[j] = t1; s2[j] = t2;
    }
#pragma unroll
    for (int o = 1; o < 16; o <<= 1)
#pragma unroll
        for (int j = 0; j < 4; ++j) {
            s1[j] += __shfl_xor(s1[j], o);
            s2[j] += __shfl_xor(s2[j], o);
        }

    float gcol[8], becol[8];
#pragma unroll
    for (int n = 0; n < 8; ++n) {
        int col = n * 16 + c;
        gcol[n] = g[col]; becol[n] = be[col];
    }

#pragma unroll
    for (int j = 0; j < 4; ++j) {
        int row = blockbase + w * 16 + q * 4 + j;
        if (row >= nseg) continue;
        float m = s1[j] * (1.f / DIM);
        float var = fmaf(-m, m, s2[j] * (1.f / DIM));
        float invs = rsqrtf(var + 1e-5f);
        unsigned short* yp = Y + (size_t)row * DIM + c;
#pragma unroll
        for (int n = 0; n < 8; ++n) {
            float d = acc[n][j] - m;
            float y = fmaxf(fmaf(d * invs, gcol[n], becol[n]), 0.f);
            unsigned int u = __builtin_bit_cast(unsigned int, y) + 0x8000u;  // half-up
            yp[n * 16] = (unsigned short)(u >> 16);   // -> global_store_short_d16_hi
        }
    }
}

// -------- kernel 5: classifier + log_softmax, quarter-wave per row, 4 rows/quarter.
#define CL_ROWS 4
__global__ __launch_bounds__(256)
void classifier_logsoftmax_v3_kernel(const uint4* __restrict__ X,
                                     const float* __restrict__ Wc,
                                     const float* __restrict__ bc,
                                     float* __restrict__ out, int nrows) {
    int w = threadIdx.x >> 6, lane = threadIdx.x & 63;
    int g = lane >> 4, c16 = lane & 15;
    int r0 = (blockIdx.x * 16 + w * 4 + g) * CL_ROWS;
    if (r0 >= nrows) return;

    float wc[8][10];
#pragma unroll
    for (int j = 0; j < 8; ++j)
#pragma unroll
        for (int c = 0; c < 10; ++c) wc[j][c] = Wc[(c16 * 8 + j) * 10 + c];
    float bcv[10];
#pragma unroll
    for (int c = 0; c < 10; ++c) bcv[c] = bc[c];

    int rend = min(r0 + CL_ROWS, nrows);
    for (int r = r0; r < rend; ++r) {
        uint4 v = X[(size_t)r * 16 + c16];
        float x[8];
        {
            unsigned int u[4] = {v.x, v.y, v.z, v.w};
#pragma unroll
            for (int i = 0; i < 4; ++i) {
                union { unsigned int ui; float f; } lo, hi;
                lo.ui = u[i] << 16;
                hi.ui = u[i] & 0xffff0000u;
                x[2 * i] = lo.f; x[2 * i + 1] = hi.f;
            }
        }
        float acc[10];
#pragma unroll
        for (int c = 0; c < 10; ++c) acc[c] = 0.f;
#pragma unroll
        for (int j = 0; j < 8; ++j)
#pragma unroll
            for (int c = 0; c < 10; ++c) acc[c] = fmaf(x[j], wc[j][c], acc[c]);

#pragma unroll
        for (int o = 1; o < 16; o <<= 1)
#pragma unroll
            for (int c = 0; c < 10; ++c) acc[c] += __shfl_xor(acc[c], o);

#pragma unroll
        for (int c = 0; c < 10; ++c) acc[c] += bcv[c];

        float mx = acc[0];
#pragma unroll
        for (int c = 1; c < 10; ++c) mx = fmaxf(mx, acc[c]);
        float se = 0.f;
#pragma unroll
        for (int c = 0; c < 10; ++c) se += expf(acc[c] - mx);
        float lse = mx + logf(se);

        float myv = 0.f;
#pragma unroll
        for (int c = 0; c < 10; ++c) myv = (c16 == c) ? acc[c] : myv;
        if (c16 < 10) out[(size_t)r * 10 + c16] = myv - lse;
    }
}

extern "C" void kernel_launch(void* const* d_in, const int* in_sizes, int n_in,
                              void* d_out, int out_size, void* d_ws, size_t ws_size,
                              hipStream_t stream) {
    const float* node_x    = (const float*)d_in[0];
    const int*   nodes_map = (const int*)d_in[1];
    const int*   edge_seg  = (const int*)d_in[2];
    const int*   edges_map = (const int*)d_in[3];
    const int*   node_seg  = (const int*)d_in[4];
    const float* W_e = (const float*)d_in[6];
    const float* b_e = (const float*)d_in[7];
    const float* g_e = (const float*)d_in[8];
    const float* be_e= (const float*)d_in[9];
    const float* W_n = (const float*)d_in[10];
    const float* b_n = (const float*)d_in[11];
    const float* g_n = (const float*)d_in[12];
    const float* be_n= (const float*)d_in[13];
    const float* W_c = (const float*)d_in[14];
    const float* b_c = (const float*)d_in[15];
    float* out = (float*)d_out;

    const int N = in_sizes[0] / DIM;           // 100000
    const int M = in_sizes[1];                 // 800000
    const int E = 200000;                      // N_EDGES (problem constant)
    const int L = in_sizes[6] / (DIM * DIM);   // 2

    // workspace carve-up
    char* ws = (char*)d_ws;
    int* edge_off = (int*)ws;           ws += align256((size_t)(E + 1) * sizeof(int));
    int* node_off = (int*)ws;           ws += align256((size_t)(N + 1) * sizeof(int));
    unsigned short* wsw = (unsigned short*)ws;      ws += align256((size_t)4 * 2048 * 8 * sizeof(unsigned short));
    int* nodes_map_pad = (int*)ws;      ws += align256((size_t)(M + 16) * sizeof(int));
    int* edges_map_pad = (int*)ws;      ws += align256((size_t)(M + 16) * sizeof(int));
    unsigned short* node_xb = (unsigned short*)ws;  ws += align256((size_t)N * DIM * sizeof(unsigned short));
    unsigned short* exb = (unsigned short*)ws;      ws += align256((size_t)E * DIM * sizeof(unsigned short));
    unsigned short* xb  = (unsigned short*)ws;      ws += align256((size_t)N * DIM * sizeof(unsigned short));
    (void)ws_size;

    setup_all_kernel<<<cdiv(N * DIM / 4, 256), 256, 0, stream>>>(
        edge_seg, M, E, edge_off, node_seg, M, N, node_off,
        node_x, node_xb, N * DIM / 4, W_e, W_n, wsw,
        nodes_map, edges_map, M, nodes_map_pad, edges_map_pad);

    const unsigned short* xcur = node_xb;
    for (int i = 0; i < L; ++i) {
        // N2E: pool node rows per hyperedge, then edge-MLP
        fused_pool_gemm_ln_relu_v13_kernel<<<cdiv(E, 128), 512, 0, stream>>>(
            (const uint4*)xcur, nodes_map_pad, edge_off, wsw + (size_t)i * 16384,
            b_e + i * DIM, g_e + i * DIM, be_e + i * DIM, exb, E);
        // E2N: pool edge rows per node, then node-MLP
        fused_pool_gemm_ln_relu_v13_kernel<<<cdiv(N, 128), 512, 0, stream>>>(
            (const uint4*)exb, edges_map_pad, node_off, wsw + (size_t)(2 + i) * 16384,
            b_n + i * DIM, g_n + i * DIM, be_n + i * DIM, xb, N);
        xcur = xb;
    }

    classifier_logsoftmax_v3_kernel<<<cdiv(N, 16 * CL_ROWS), 256, 0, stream>>>(
        (const uint4*)xcur, W_c, b_c, out, N);
}

// Round 8
// 333.190 us; speedup vs baseline: 1.1348x; 1.0210x over previous
//
#include <hip/hip_runtime.h>
#include <hip/hip_bf16.h>

#define DIM 128

typedef __bf16 bf16x8 __attribute__((ext_vector_type(8)));
typedef float f32x4 __attribute__((ext_vector_type(4)));
typedef float f32x2 __attribute__((ext_vector_type(2)));

static inline int cdiv(int a, int b) { return (a + b - 1) / b; }
static inline size_t align256(size_t x) { return (x + 255) & ~size_t(255); }

__device__ inline unsigned short f2bf(float f) {
    union { float f; unsigned int u; } v; v.f = f;
    unsigned int r = v.u + 0x7fff + ((v.u >> 16) & 1);   // RNE
    return (unsigned short)(r >> 16);
}
__device__ inline unsigned int hb(float f) {             // half-up bf16, 2 ops
    return (__builtin_bit_cast(unsigned int, f) + 0x8000u) >> 16;
}

// -------- setup (merged): segment offsets (both tables) + fp32->bf16 convert
// + W swizzle, one launch (R2 version — v8 needs no padded maps).
__global__ void setup_all_kernel(const int* __restrict__ segA, int mA, int nA,
                                 int* __restrict__ offA,
                                 const int* __restrict__ segB, int mB, int nB,
                                 int* __restrict__ offB,
                                 const float* __restrict__ xin,
                                 unsigned short* __restrict__ xout, int n4,
                                 const float* __restrict__ W_e,
                                 const float* __restrict__ W_n,
                                 unsigned short* __restrict__ wsw) {
    int gid = blockIdx.x * blockDim.x + threadIdx.x;

    // job B: fp32 -> bf16 convert (bulk of the work, n4 = N*DIM/4 threads)
    if (gid < n4) {
        float4 v = ((const float4*)xin)[gid];
        ushort4 o;
        o.x = f2bf(v.x); o.y = f2bf(v.y); o.z = f2bf(v.z); o.w = f2bf(v.w);
        ((ushort4*)xout)[gid] = o;
    }

    // job A: segment-offset tables via binary search
    if (gid <= nA) {
        int lo = 0, hi = mA;
        while (lo < hi) { int mid = (lo + hi) >> 1; if (segA[mid] < gid) lo = mid + 1; else hi = mid; }
        offA[gid] = lo;
    }
    int jj = gid - (nA + 1);
    if (jj >= 0 && jj <= nB) {
        int lo = 0, hi = mB;
        while (lo < hi) { int mid = (lo + hi) >> 1; if (segB[mid] < jj) lo = mid + 1; else hi = mid; }
        offB[jj] = lo;
    }

    // job C: pre-swizzle W (4 matrices of 128x128 fp32) into frag-major bf16
    if (gid < 8192) {
        int mi = gid >> 11;
        int e = gid & 2047;
        const float* W = (mi < 2) ? (W_e + (size_t)mi * DIM * DIM)
                                  : (W_n + (size_t)(mi - 2) * DIM * DIM);
        int t = e >> 9, n = (e >> 6) & 7, lane = e & 63;
        int q = lane >> 4, c = lane & 15;
        int k0 = t * 32 + q * 8, col = n * 16 + c;
        unsigned short vals[8];
#pragma unroll
        for (int j = 0; j < 8; ++j) vals[j] = f2bf(W[(size_t)(k0 + j) * DIM + col]);
        ushort4* dst = (ushort4*)(wsw + (size_t)gid * 8);
        dst[0] = make_ushort4(vals[0], vals[1], vals[2], vals[3]);
        dst[1] = make_ushort4(vals[4], vals[5], vals[6], vals[7]);
    }
}

// bf16 accumulate: 3 VALU/uint (hi = direct bitcast; validated since v7)
__device__ inline void accum8(float* a, uint4 v) {
    unsigned int u[4] = {v.x, v.y, v.z, v.w};
#pragma unroll
    for (int i = 0; i < 4; ++i) {
        a[2 * i]     += __builtin_bit_cast(float, u[i] << 16);
        a[2 * i + 1] += __builtin_bit_cast(float, u[i]);
    }
}
// fp8 e4m3 accumulate: 8 bytes -> 8 floats via 4 packed hardware converts
__device__ inline void accum8f8(float* a, uint2 v) {
    f32x2 p;
    p = __builtin_amdgcn_cvt_pk_f32_fp8((int)v.x, false); a[0] += p[0]; a[1] += p[1];
    p = __builtin_amdgcn_cvt_pk_f32_fp8((int)v.x, true);  a[2] += p[0]; a[3] += p[1];
    p = __builtin_amdgcn_cvt_pk_f32_fp8((int)v.y, false); a[4] += p[0]; a[5] += p[1];
    p = __builtin_amdgcn_cvt_pk_f32_fp8((int)v.y, true);  a[6] += p[0]; a[7] += p[1];
}

// -------- kernel 4 v14: v8 structure (direct-fragment pooling, W in LDS,
// no A-tile, single barrier, 512 thr) templated on I/O precision.
// R7 conclusion: 3 structures (depth 1-8, occ 19-44%) all hit ~55us =>
// random-gather memory-system equilibrium (~205MB @ ~3.7TB/s). The lever
// is BYTES: edge features (exb, internal-only) go fp8-e4m3. N2E writes
// fp8 rows (128B); E2N gathers 128B rows (one cache line) and decodes with
// v_cvt_pk_f32_fp8 during accumulation. Node-side tensors + GEMM stay bf16.
// Encode+decode both ours => format round-trip self-consistent.
template<bool IN8, bool OUT8>
__global__ __launch_bounds__(512)
void fused_pool_gemm_ln_relu_v14_kernel(const void* __restrict__ src,
                                        const int* __restrict__ map,
                                        const int* __restrict__ off,
                                        const unsigned short* __restrict__ Wsw,
                                        const float* __restrict__ b,
                                        const float* __restrict__ g,
                                        const float* __restrict__ be,
                                        void* __restrict__ Y,
                                        int nseg) {
    __shared__ bf16x8 wlds[2048];              // 32 KB frag-major W (only LDS)
    int tid = threadIdx.x;
    int w = tid >> 6, lane = tid & 63;
    int q = lane >> 4, c = lane & 15;

    {   // stage swizzled W (global layout == LDS layout)
        const uint4* gsrc = (const uint4*)Wsw;
        uint4* ldst = (uint4*)wlds;
#pragma unroll
        for (int i = 0; i < 4; ++i) ldst[tid + i * 512] = gsrc[tid + i * 512];
    }

    int blockbase = blockIdx.x * 128;
    int seg = min(blockbase + w * 16 + c, nseg - 1);
    int beg = off[seg], end = off[seg + 1];
    int e1 = max(end - 1, 0);
    unsigned r = (unsigned)map[min(beg, e1)];   // first member, issued pre-barrier

    __syncthreads();   // only barrier: W visible to all waves

    // ---- phase 1: pool in A-fragment layout. Lane (q,c): segment w*16+c,
    // chunk t of the member row (features q*8 + t*32 .. +8).
    float a[4][8];
#pragma unroll
    for (int t = 0; t < 4; ++t)
#pragma unroll
        for (int i = 0; i < 8; ++i) a[t][i] = 0.f;

    const char* sbase = (const char*)src;
    if constexpr (!IN8) {
        unsigned qb = (unsigned)(q << 4);          // bf16 rows: 256 B
        for (int j = beg; j < end; ++j) {
            const char* p = sbase + ((r << 8) + qb);
            uint4 v0 = *(const uint4*)(p);
            uint4 v1 = *(const uint4*)(p + 64);
            uint4 v2 = *(const uint4*)(p + 128);
            uint4 v3 = *(const uint4*)(p + 192);
            unsigned rn = (unsigned)map[min(j + 1, e1)];   // prefetch next index
            accum8(a[0], v0);
            accum8(a[1], v1);
            accum8(a[2], v2);
            accum8(a[3], v3);
            r = rn;
        }
    } else {
        unsigned qb = (unsigned)(q << 3);          // fp8 rows: 128 B (one line)
        for (int j = beg; j < end; ++j) {
            const char* p = sbase + ((r << 7) + qb);
            uint2 v0 = *(const uint2*)(p);
            uint2 v1 = *(const uint2*)(p + 32);
            uint2 v2 = *(const uint2*)(p + 64);
            uint2 v3 = *(const uint2*)(p + 96);
            unsigned rn = (unsigned)map[min(j + 1, e1)];   // prefetch next index
            accum8f8(a[0], v0);
            accum8f8(a[1], v1);
            accum8f8(a[2], v2);
            accum8f8(a[3], v3);
            r = rn;
        }
    }

    // mean + convert to bf16 A-fragments (in-register)
    float inv = 1.f / fmaxf((float)(end - beg), 1.f);
    bf16x8 af[4];
#pragma unroll
    for (int t = 0; t < 4; ++t) {
        uint4 o;
        o.x = hb(a[t][0] * inv) | (hb(a[t][1] * inv) << 16);
        o.y = hb(a[t][2] * inv) | (hb(a[t][3] * inv) << 16);
        o.z = hb(a[t][4] * inv) | (hb(a[t][5] * inv) << 16);
        o.w = hb(a[t][6] * inv) | (hb(a[t][7] * inv) << 16);
        af[t] = __builtin_bit_cast(bf16x8, o);
    }

    // bias (seeds acc); g/be deferred past MFMA to cap pressure
    float bcol[8];
#pragma unroll
    for (int n = 0; n < 8; ++n) bcol[n] = b[n * 16 + c];

    f32x4 acc[8];
#pragma unroll
    for (int n = 0; n < 8; ++n) acc[n] = f32x4{bcol[n], bcol[n], bcol[n], bcol[n]};

    // ---- phase 2: GEMM from register A-fragments (no barrier needed)
#pragma unroll
    for (int n = 0; n < 8; ++n) {
        acc[n] = __builtin_amdgcn_mfma_f32_16x16x32_bf16(af[0], wlds[(0 * 8 + n) * 64 + lane], acc[n], 0, 0, 0);
        acc[n] = __builtin_amdgcn_mfma_f32_16x16x32_bf16(af[1], wlds[(1 * 8 + n) * 64 + lane], acc[n], 0, 0, 0);
        acc[n] = __builtin_amdgcn_mfma_f32_16x16x32_bf16(af[2], wlds[(2 * 8 + n) * 64 + lane], acc[n], 0, 0, 0);
        acc[n] = __builtin_amdgcn_mfma_f32_16x16x32_bf16(af[3], wlds[(3 * 8 + n) * 64 + lane], acc[n], 0, 0, 0);
    }

    // LN sums per row (lane's rows: blockbase + w*16 + q*4 + j, col n*16+c)
    float s1[4], s2[4];
#pragma unroll
    for (int j = 0; j < 4; ++j) {
        float t1 = 0.f, t2 = 0.f;
#pragma unroll
        for (int n = 0; n < 8; ++n) { float v = acc[n][j]; t1 += v; t2 = fmaf(v, v, t2); }
        s1[j] = t1; s2[j] = t2;
    }
#pragma unroll
    for (int o = 1; o < 16; o <<= 1)
#pragma unroll
        for (int j = 0; j < 4; ++j) {
            s1[j] += __shfl_xor(s1[j], o);
            s2[j] += __shfl_xor(s2[j], o);
        }

    float gcol[8], becol[8];
#pragma unroll
    for (int n = 0; n < 8; ++n) {
        int col = n * 16 + c;
        gcol[n] = g[col]; becol[n] = be[col];
    }

#pragma unroll
    for (int j = 0; j < 4; ++j) {
        int row = blockbase + w * 16 + q * 4 + j;
        if (row >= nseg) continue;
        float m = s1[j] * (1.f / DIM);
        float var = fmaf(-m, m, s2[j] * (1.f / DIM));
        float invs = rsqrtf(var + 1e-5f);
        if constexpr (!OUT8) {
            unsigned short* yp = (unsigned short*)Y + (size_t)row * DIM + c;
#pragma unroll
            for (int n = 0; n < 8; ++n) {
                float d = acc[n][j] - m;
                float y = fmaxf(fmaf(d * invs, gcol[n], becol[n]), 0.f);
                unsigned int u = __builtin_bit_cast(unsigned int, y) + 0x8000u;  // half-up
                yp[n * 16] = (unsigned short)(u >> 16);
            }
        } else {
            unsigned char* yp = (unsigned char*)Y + (size_t)row * DIM + c;
#pragma unroll
            for (int n = 0; n < 8; ++n) {
                float d = acc[n][j] - m;
                float y = fmaxf(fmaf(d * invs, gcol[n], becol[n]), 0.f);
                int e = __builtin_amdgcn_cvt_pk_fp8_f32(y, y, 0, false);
                yp[n * 16] = (unsigned char)e;
            }
        }
    }
}

// -------- kernel 5: classifier + log_softmax, quarter-wave per row, 4 rows/quarter.
#define CL_ROWS 4
__global__ __launch_bounds__(256)
void classifier_logsoftmax_v3_kernel(const uint4* __restrict__ X,
                                     const float* __restrict__ Wc,
                                     const float* __restrict__ bc,
                                     float* __restrict__ out, int nrows) {
    int w = threadIdx.x >> 6, lane = threadIdx.x & 63;
    int g = lane >> 4, c16 = lane & 15;
    int r0 = (blockIdx.x * 16 + w * 4 + g) * CL_ROWS;
    if (r0 >= nrows) return;

    float wc[8][10];
#pragma unroll
    for (int j = 0; j < 8; ++j)
#pragma unroll
        for (int c = 0; c < 10; ++c) wc[j][c] = Wc[(c16 * 8 + j) * 10 + c];
    float bcv[10];
#pragma unroll
    for (int c = 0; c < 10; ++c) bcv[c] = bc[c];

    int rend = min(r0 + CL_ROWS, nrows);
    for (int r = r0; r < rend; ++r) {
        uint4 v = X[(size_t)r * 16 + c16];
        float x[8];
        {
            unsigned int u[4] = {v.x, v.y, v.z, v.w};
#pragma unroll
            for (int i = 0; i < 4; ++i) {
                union { unsigned int ui; float f; } lo, hi;
                lo.ui = u[i] << 16;
                hi.ui = u[i] & 0xffff0000u;
                x[2 * i] = lo.f; x[2 * i + 1] = hi.f;
            }
        }
        float acc[10];
#pragma unroll
        for (int c = 0; c < 10; ++c) acc[c] = 0.f;
#pragma unroll
        for (int j = 0; j < 8; ++j)
#pragma unroll
            for (int c = 0; c < 10; ++c) acc[c] = fmaf(x[j], wc[j][c], acc[c]);

#pragma unroll
        for (int o = 1; o < 16; o <<= 1)
#pragma unroll
            for (int c = 0; c < 10; ++c) acc[c] += __shfl_xor(acc[c], o);

#pragma unroll
        for (int c = 0; c < 10; ++c) acc[c] += bcv[c];

        float mx = acc[0];
#pragma unroll
        for (int c = 1; c < 10; ++c) mx = fmaxf(mx, acc[c]);
        float se = 0.f;
#pragma unroll
        for (int c = 0; c < 10; ++c) se += expf(acc[c] - mx);
        float lse = mx + logf(se);

        float myv = 0.f;
#pragma unroll
        for (int c = 0; c < 10; ++c) myv = (c16 == c) ? acc[c] : myv;
        if (c16 < 10) out[(size_t)r * 10 + c16] = myv - lse;
    }
}

extern "C" void kernel_launch(void* const* d_in, const int* in_sizes, int n_in,
                              void* d_out, int out_size, void* d_ws, size_t ws_size,
                              hipStream_t stream) {
    const float* node_x    = (const float*)d_in[0];
    const int*   nodes_map = (const int*)d_in[1];
    const int*   edge_seg  = (const int*)d_in[2];
    const int*   edges_map = (const int*)d_in[3];
    const int*   node_seg  = (const int*)d_in[4];
    const float* W_e = (const float*)d_in[6];
    const float* b_e = (const float*)d_in[7];
    const float* g_e = (const float*)d_in[8];
    const float* be_e= (const float*)d_in[9];
    const float* W_n = (const float*)d_in[10];
    const float* b_n = (const float*)d_in[11];
    const float* g_n = (const float*)d_in[12];
    const float* be_n= (const float*)d_in[13];
    const float* W_c = (const float*)d_in[14];
    const float* b_c = (const float*)d_in[15];
    float* out = (float*)d_out;

    const int N = in_sizes[0] / DIM;           // 100000
    const int M = in_sizes[1];                 // 800000
    const int E = 200000;                      // N_EDGES (problem constant)
    const int L = in_sizes[6] / (DIM * DIM);   // 2

    // workspace carve-up (exb now fp8: E*128 bytes)
    char* ws = (char*)d_ws;
    int* edge_off = (int*)ws;           ws += align256((size_t)(E + 1) * sizeof(int));
    int* node_off = (int*)ws;           ws += align256((size_t)(N + 1) * sizeof(int));
    unsigned short* wsw = (unsigned short*)ws;      ws += align256((size_t)4 * 2048 * 8 * sizeof(unsigned short));
    unsigned short* node_xb = (unsigned short*)ws;  ws += align256((size_t)N * DIM * sizeof(unsigned short));
    unsigned char* exb = (unsigned char*)ws;        ws += align256((size_t)E * DIM);
    unsigned short* xb  = (unsigned short*)ws;      ws += align256((size_t)N * DIM * sizeof(unsigned short));
    (void)ws_size;

    setup_all_kernel<<<cdiv(N * DIM / 4, 256), 256, 0, stream>>>(
        edge_seg, M, E, edge_off, node_seg, M, N, node_off,
        node_x, node_xb, N * DIM / 4, W_e, W_n, wsw);

    const unsigned short* xcur = node_xb;
    for (int i = 0; i < L; ++i) {
        // N2E: pool bf16 node rows per hyperedge, edge-MLP, write fp8 edge rows
        fused_pool_gemm_ln_relu_v14_kernel<false, true><<<cdiv(E, 128), 512, 0, stream>>>(
            (const void*)xcur, nodes_map, edge_off, wsw + (size_t)i * 16384,
            b_e + i * DIM, g_e + i * DIM, be_e + i * DIM, (void*)exb, E);
        // E2N: pool fp8 edge rows per node, node-MLP, write bf16 node rows
        fused_pool_gemm_ln_relu_v14_kernel<true, false><<<cdiv(N, 128), 512, 0, stream>>>(
            (const void*)exb, edges_map, node_off, wsw + (size_t)(2 + i) * 16384,
            b_n + i * DIM, g_n + i * DIM, be_n + i * DIM, (void*)xb, N);
        xcur = xb;
    }

    classifier_logsoftmax_v3_kernel<<<cdiv(N, 16 * CL_ROWS), 256, 0, stream>>>(
        (const uint4*)xcur, W_c, b_c, out, N);
}

// Round 10
// 307.990 us; speedup vs baseline: 1.2276x; 1.0818x over previous
//
#include <hip/hip_runtime.h>
#include <hip/hip_bf16.h>

#define DIM 128

typedef __bf16 bf16x8 __attribute__((ext_vector_type(8)));
typedef float f32x4 __attribute__((ext_vector_type(4)));
typedef float f32x2 __attribute__((ext_vector_type(2)));

static inline int cdiv(int a, int b) { return (a + b - 1) / b; }
static inline size_t align256(size_t x) { return (x + 255) & ~size_t(255); }

__device__ inline unsigned short f2bf(float f) {
    union { float f; unsigned int u; } v; v.f = f;
    unsigned int r = v.u + 0x7fff + ((v.u >> 16) & 1);   // RNE
    return (unsigned short)(r >> 16);
}
__device__ inline unsigned int hb(float f) {             // half-up bf16, 2 ops
    return (__builtin_bit_cast(unsigned int, f) + 0x8000u) >> 16;
}

// -------- setup (merged): segment offsets (both tables) + fp32->bf16 convert
// + W swizzle, one launch.
__global__ void setup_all_kernel(const int* __restrict__ segA, int mA, int nA,
                                 int* __restrict__ offA,
                                 const int* __restrict__ segB, int mB, int nB,
                                 int* __restrict__ offB,
                                 const float* __restrict__ xin,
                                 unsigned short* __restrict__ xout, int n4,
                                 const float* __restrict__ W_e,
                                 const float* __restrict__ W_n,
                                 unsigned short* __restrict__ wsw) {
    int gid = blockIdx.x * blockDim.x + threadIdx.x;

    // job B: fp32 -> bf16 convert (bulk of the work, n4 = N*DIM/4 threads)
    if (gid < n4) {
        float4 v = ((const float4*)xin)[gid];
        ushort4 o;
        o.x = f2bf(v.x); o.y = f2bf(v.y); o.z = f2bf(v.z); o.w = f2bf(v.w);
        ((ushort4*)xout)[gid] = o;
    }

    // job A: segment-offset tables via binary search
    if (gid <= nA) {
        int lo = 0, hi = mA;
        while (lo < hi) { int mid = (lo + hi) >> 1; if (segA[mid] < gid) lo = mid + 1; else hi = mid; }
        offA[gid] = lo;
    }
    int jj = gid - (nA + 1);
    if (jj >= 0 && jj <= nB) {
        int lo = 0, hi = mB;
        while (lo < hi) { int mid = (lo + hi) >> 1; if (segB[mid] < jj) lo = mid + 1; else hi = mid; }
        offB[jj] = lo;
    }

    // job C: pre-swizzle W (4 matrices of 128x128 fp32) into frag-major bf16
    if (gid < 8192) {
        int mi = gid >> 11;
        int e = gid & 2047;
        const float* W = (mi < 2) ? (W_e + (size_t)mi * DIM * DIM)
                                  : (W_n + (size_t)(mi - 2) * DIM * DIM);
        int t = e >> 9, n = (e >> 6) & 7, lane = e & 63;
        int q = lane >> 4, c = lane & 15;
        int k0 = t * 32 + q * 8, col = n * 16 + c;
        unsigned short vals[8];
#pragma unroll
        for (int j = 0; j < 8; ++j) vals[j] = f2bf(W[(size_t)(k0 + j) * DIM + col]);
        ushort4* dst = (ushort4*)(wsw + (size_t)gid * 8);
        dst[0] = make_ushort4(vals[0], vals[1], vals[2], vals[3]);
        dst[1] = make_ushort4(vals[4], vals[5], vals[6], vals[7]);
    }
}

// bf16 accumulate: 3 VALU/uint (hi = direct bitcast; validated since v7)
__device__ inline void accum8(float* a, uint4 v) {
    unsigned int u[4] = {v.x, v.y, v.z, v.w};
#pragma unroll
    for (int i = 0; i < 4; ++i) {
        a[2 * i]     += __builtin_bit_cast(float, u[i] << 16);
        a[2 * i + 1] += __builtin_bit_cast(float, u[i]);
    }
}
// fp8 e4m3 accumulate: uint4 = 16 bytes = 16 features -> 16 f32 adds
__device__ inline void accum16f8(float* a, uint4 v) {
    unsigned int u[4] = {v.x, v.y, v.z, v.w};
#pragma unroll
    for (int d = 0; d < 4; ++d) {
        f32x2 p0 = __builtin_amdgcn_cvt_pk_f32_fp8((int)u[d], false);
        f32x2 p1 = __builtin_amdgcn_cvt_pk_f32_fp8((int)u[d], true);
        a[4 * d + 0] += p0[0]; a[4 * d + 1] += p0[1];
        a[4 * d + 2] += p1[0]; a[4 * d + 3] += p1[1];
    }
}

// -------- kernel 4 v15: v14 (direct-fragment pooling, W in LDS, single
// barrier) with the fp8 gather restructured to HALF THE REQUEST COUNT.
// R8 datum: halving bytes AND lines (fp8 uint2 path) changed nothing =>
// the gather floor is per-lane REQUEST rate. v15 fp8 path: lane (q,c)
// loads TWO uint4 units (features [16*xa,+16),[16*xb,+16), xa=(q>>1)+4(q&1),
// xb=xa+2) -> 8 requests/row across the 4 q-lanes instead of 16. Halves of
// each unit are swapped with lane^16 ONCE PER SEGMENT after the mean
// (8 shfl_xor), then fragments assemble via q&1 selects. Bit-exact vs v14.
template<bool IN8, bool OUT8>
__global__ __launch_bounds__(512)
void fused_pool_gemm_ln_relu_v15_kernel(const void* __restrict__ src,
                                        const int* __restrict__ map,
                                        const int* __restrict__ off,
                                        const unsigned short* __restrict__ Wsw,
                                        const float* __restrict__ b,
                                        const float* __restrict__ g,
                                        const float* __restrict__ be,
                                        void* __restrict__ Y,
                                        int nseg) {
    __shared__ bf16x8 wlds[2048];              // 32 KB frag-major W (only LDS)
    int tid = threadIdx.x;
    int w = tid >> 6, lane = tid & 63;
    int q = lane >> 4, c = lane & 15;

    {   // stage swizzled W (global layout == LDS layout)
        const uint4* gsrc = (const uint4*)Wsw;
        uint4* ldst = (uint4*)wlds;
#pragma unroll
        for (int i = 0; i < 4; ++i) ldst[tid + i * 512] = gsrc[tid + i * 512];
    }

    int blockbase = blockIdx.x * 128;
    int seg = min(blockbase + w * 16 + c, nseg - 1);
    int beg = off[seg], end = off[seg + 1];
    int e1 = max(end - 1, 0);
    unsigned r = (unsigned)map[min(beg, e1)];   // first member, issued pre-barrier

    __syncthreads();   // only barrier: W visible to all waves

    const char* sbase = (const char*)src;
    float inv;
    bf16x8 af[4];

    if constexpr (!IN8) {
        // ---- bf16 rows (256 B): fragment-layout pooling, 16B/lane x4 (minimal)
        float a[4][8];
#pragma unroll
        for (int t = 0; t < 4; ++t)
#pragma unroll
            for (int i = 0; i < 8; ++i) a[t][i] = 0.f;

        unsigned qb = (unsigned)(q << 4);
        for (int j = beg; j < end; ++j) {
            const char* p = sbase + ((r << 8) + qb);
            uint4 v0 = *(const uint4*)(p);
            uint4 v1 = *(const uint4*)(p + 64);
            uint4 v2 = *(const uint4*)(p + 128);
            uint4 v3 = *(const uint4*)(p + 192);
            unsigned rn = (unsigned)map[min(j + 1, e1)];   // prefetch next index
            accum8(a[0], v0);
            accum8(a[1], v1);
            accum8(a[2], v2);
            accum8(a[3], v3);
            r = rn;
        }
        inv = 1.f / fmaxf((float)(end - beg), 1.f);
#pragma unroll
        for (int t = 0; t < 4; ++t) {
            uint4 o;
            o.x = hb(a[t][0] * inv) | (hb(a[t][1] * inv) << 16);
            o.y = hb(a[t][2] * inv) | (hb(a[t][3] * inv) << 16);
            o.z = hb(a[t][4] * inv) | (hb(a[t][5] * inv) << 16);
            o.w = hb(a[t][6] * inv) | (hb(a[t][7] * inv) << 16);
            af[t] = __builtin_bit_cast(bf16x8, o);
        }
    } else {
        // ---- fp8 rows (128 B): unit-layout pooling, 2 x uint4 per lane
        float a0[16], a1[16];
#pragma unroll
        for (int i = 0; i < 16; ++i) { a0[i] = 0.f; a1[i] = 0.f; }

        unsigned qb = 16u * ((unsigned)(q >> 1) + 4u * (unsigned)(q & 1));
        for (int j = beg; j < end; ++j) {
            const char* p = sbase + ((r << 7) + qb);
            uint4 u0 = *(const uint4*)(p);
            uint4 u1 = *(const uint4*)(p + 32);
            unsigned rn = (unsigned)map[min(j + 1, e1)];   // prefetch next index
            accum16f8(a0, u0);
            accum16f8(a1, u1);
            r = rn;
        }
        inv = 1.f / fmaxf((float)(end - beg), 1.f);

        // mean + pack each unit to 8 dwords (16 bf16)
        unsigned pk0[8], pk1[8];
#pragma unroll
        for (int j = 0; j < 8; ++j) {
            pk0[j] = hb(a0[2 * j] * inv) | (hb(a0[2 * j + 1] * inv) << 16);
            pk1[j] = hb(a1[2 * j] * inv) | (hb(a1[2 * j + 1] * inv) << 16);
        }
        int h = q & 1;   // my half within each unit
        // exchange: send partner's half (h? j=0..3 : j=4..7), keep own
        unsigned own0[4], own1[4], rec0[4], rec1[4];
#pragma unroll
        for (int k = 0; k < 4; ++k) {
            unsigned s0 = h ? pk0[k] : pk0[k + 4];
            unsigned s1 = h ? pk1[k] : pk1[k + 4];
            rec0[k] = (unsigned)__shfl_xor((int)s0, 16);
            rec1[k] = (unsigned)__shfl_xor((int)s1, 16);
            own0[k] = h ? pk0[k + 4] : pk0[k];
            own1[k] = h ? pk1[k + 4] : pk1[k];
        }
        // assemble fragments: h==0: own->(t0,t1), rec->(t2,t3); h==1 swapped
        unsigned f0[4], f1[4], f2[4], f3[4];
#pragma unroll
        for (int k = 0; k < 4; ++k) {
            f0[k] = h ? rec0[k] : own0[k];
            f1[k] = h ? rec1[k] : own1[k];
            f2[k] = h ? own0[k] : rec0[k];
            f3[k] = h ? own1[k] : rec1[k];
        }
        af[0] = __builtin_bit_cast(bf16x8, make_uint4(f0[0], f0[1], f0[2], f0[3]));
        af[1] = __builtin_bit_cast(bf16x8, make_uint4(f1[0], f1[1], f1[2], f1[3]));
        af[2] = __builtin_bit_cast(bf16x8, make_uint4(f2[0], f2[1], f2[2], f2[3]));
        af[3] = __builtin_bit_cast(bf16x8, make_uint4(f3[0], f3[1], f3[2], f3[3]));
    }

    // bias (seeds acc); g/be deferred past MFMA to cap pressure
    float bcol[8];
#pragma unroll
    for (int n = 0; n < 8; ++n) bcol[n] = b[n * 16 + c];

    f32x4 acc[8];
#pragma unroll
    for (int n = 0; n < 8; ++n) acc[n] = f32x4{bcol[n], bcol[n], bcol[n], bcol[n]};

    // ---- phase 2: GEMM from register A-fragments (no barrier needed)
#pragma unroll
    for (int n = 0; n < 8; ++n) {
        acc[n] = __builtin_amdgcn_mfma_f32_16x16x32_bf16(af[0], wlds[(0 * 8 + n) * 64 + lane], acc[n], 0, 0, 0);
        acc[n] = __builtin_amdgcn_mfma_f32_16x16x32_bf16(af[1], wlds[(1 * 8 + n) * 64 + lane], acc[n], 0, 0, 0);
        acc[n] = __builtin_amdgcn_mfma_f32_16x16x32_bf16(af[2], wlds[(2 * 8 + n) * 64 + lane], acc[n], 0, 0, 0);
        acc[n] = __builtin_amdgcn_mfma_f32_16x16x32_bf16(af[3], wlds[(3 * 8 + n) * 64 + lane], acc[n], 0, 0, 0);
    }

    // LN sums per row (lane's rows: blockbase + w*16 + q*4 + j, col n*16+c)
    float s1[4], s2[4];
#pragma unroll
    for (int j = 0; j < 4; ++j) {
        float t1 = 0.f, t2 = 0.f;
#pragma unroll
        for (int n = 0; n < 8; ++n) { float v = acc[n][j]; t1 += v; t2 = fmaf(v, v, t2); }
        s1[j] = t1; s2[j] = t2;
    }
#pragma unroll
    for (int o = 1; o < 16; o <<= 1)
#pragma unroll
        for (int j = 0; j < 4; ++j) {
            s1[j] += __shfl_xor(s1[j], o);
            s2[j] += __shfl_xor(s2[j], o);
        }

    float gcol[8], becol[8];
#pragma unroll
    for (int n = 0; n < 8; ++n) {
        int col = n * 16 + c;
        gcol[n] = g[col]; becol[n] = be[col];
    }

#pragma unroll
    for (int j = 0; j < 4; ++j) {
        int row = blockbase + w * 16 + q * 4 + j;
        if (row >= nseg) continue;
        float m = s1[j] * (1.f / DIM);
        float var = fmaf(-m, m, s2[j] * (1.f / DIM));
        float invs = rsqrtf(var + 1e-5f);
        if constexpr (!OUT8) {
            unsigned short* yp = (unsigned short*)Y + (size_t)row * DIM + c;
#pragma unroll
            for (int n = 0; n < 8; ++n) {
                float d = acc[n][j] - m;
                float y = fmaxf(fmaf(d * invs, gcol[n], becol[n]), 0.f);
                unsigned int u = __builtin_bit_cast(unsigned int, y) + 0x8000u;  // half-up
                yp[n * 16] = (unsigned short)(u >> 16);
            }
        } else {
            unsigned char* yp = (unsigned char*)Y + (size_t)row * DIM + c;
#pragma unroll
            for (int n = 0; n < 8; ++n) {
                float d = acc[n][j] - m;
                float y = fmaxf(fmaf(d * invs, gcol[n], becol[n]), 0.f);
                int e = __builtin_amdgcn_cvt_pk_fp8_f32(y, y, 0, false);
                yp[n * 16] = (unsigned char)e;
            }
        }
    }
}

// -------- kernel 5: classifier + log_softmax, quarter-wave per row, 4 rows/quarter.
#define CL_ROWS 4
__global__ __launch_bounds__(256)
void classifier_logsoftmax_v3_kernel(const uint4* __restrict__ X,
                                     const float* __restrict__ Wc,
                                     const float* __restrict__ bc,
                                     float* __restrict__ out, int nrows) {
    int w = threadIdx.x >> 6, lane = threadIdx.x & 63;
    int g = lane >> 4, c16 = lane & 15;
    int r0 = (blockIdx.x * 16 + w * 4 + g) * CL_ROWS;
    if (r0 >= nrows) return;

    float wc[8][10];
#pragma unroll
    for (int j = 0; j < 8; ++j)
#pragma unroll
        for (int c = 0; c < 10; ++c) wc[j][c] = Wc[(c16 * 8 + j) * 10 + c];
    float bcv[10];
#pragma unroll
    for (int c = 0; c < 10; ++c) bcv[c] = bc[c];

    int rend = min(r0 + CL_ROWS, nrows);
    for (int r = r0; r < rend; ++r) {
        uint4 v = X[(size_t)r * 16 + c16];
        float x[8];
        {
            unsigned int u[4] = {v.x, v.y, v.z, v.w};
#pragma unroll
            for (int i = 0; i < 4; ++i) {
                union { unsigned int ui; float f; } lo, hi;
                lo.ui = u[i] << 16;
                hi.ui = u[i] & 0xffff0000u;
                x[2 * i] = lo.f; x[2 * i + 1] = hi.f;
            }
        }
        float acc[10];
#pragma unroll
        for (int c = 0; c < 10; ++c) acc[c] = 0.f;
#pragma unroll
        for (int j = 0; j < 8; ++j)
#pragma unroll
            for (int c = 0; c < 10; ++c) acc[c] = fmaf(x[j], wc[j][c], acc[c]);

#pragma unroll
        for (int o = 1; o < 16; o <<= 1)
#pragma unroll
            for (int c = 0; c < 10; ++c) acc[c] += __shfl_xor(acc[c], o);

#pragma unroll
        for (int c = 0; c < 10; ++c) acc[c] += bcv[c];

        float mx = acc[0];
#pragma unroll
        for (int c = 1; c < 10; ++c) mx = fmaxf(mx, acc[c]);
        float se = 0.f;
#pragma unroll
        for (int c = 0; c < 10; ++c) se += expf(acc[c] - mx);
        float lse = mx + logf(se);

        float myv = 0.f;
#pragma unroll
        for (int c = 0; c < 10; ++c) myv = (c16 == c) ? acc[c] : myv;
        if (c16 < 10) out[(size_t)r * 10 + c16] = myv - lse;
    }
}

extern "C" void kernel_launch(void* const* d_in, const int* in_sizes, int n_in,
                              void* d_out, int out_size, void* d_ws, size_t ws_size,
                              hipStream_t stream) {
    const float* node_x    = (const float*)d_in[0];
    const int*   nodes_map = (const int*)d_in[1];
    const int*   edge_seg  = (const int*)d_in[2];
    const int*   edges_map = (const int*)d_in[3];
    const int*   node_seg  = (const int*)d_in[4];
    const float* W_e = (const float*)d_in[6];
    const float* b_e = (const float*)d_in[7];
    const float* g_e = (const float*)d_in[8];
    const float* be_e= (const float*)d_in[9];
    const float* W_n = (const float*)d_in[10];
    const float* b_n = (const float*)d_in[11];
    const float* g_n = (const float*)d_in[12];
    const float* be_n= (const float*)d_in[13];
    const float* W_c = (const float*)d_in[14];
    const float* b_c = (const float*)d_in[15];
    float* out = (float*)d_out;

    const int N = in_sizes[0] / DIM;           // 100000
    const int M = in_sizes[1];                 // 800000
    const int E = 200000;                      // N_EDGES (problem constant)
    const int L = in_sizes[6] / (DIM * DIM);   // 2

    // workspace carve-up (exb fp8: E*128 bytes)
    char* ws = (char*)d_ws;
    int* edge_off = (int*)ws;           ws += align256((size_t)(E + 1) * sizeof(int));
    int* node_off = (int*)ws;           ws += align256((size_t)(N + 1) * sizeof(int));
    unsigned short* wsw = (unsigned short*)ws;      ws += align256((size_t)4 * 2048 * 8 * sizeof(unsigned short));
    unsigned short* node_xb = (unsigned short*)ws;  ws += align256((size_t)N * DIM * sizeof(unsigned short));
    unsigned char* exb = (unsigned char*)ws;        ws += align256((size_t)E * DIM);
    unsigned short* xb  = (unsigned short*)ws;      ws += align256((size_t)N * DIM * sizeof(unsigned short));
    (void)ws_size;

    setup_all_kernel<<<cdiv(N * DIM / 4, 256), 256, 0, stream>>>(
        edge_seg, M, E, edge_off, node_seg, M, N, node_off,
        node_x, node_xb, N * DIM / 4, W_e, W_n, wsw);

    const unsigned short* xcur = node_xb;
    for (int i = 0; i < L; ++i) {
        // N2E: pool bf16 node rows per hyperedge, edge-MLP, write fp8 edge rows
        fused_pool_gemm_ln_relu_v15_kernel<false, true><<<cdiv(E, 128), 512, 0, stream>>>(
            (const void*)xcur, nodes_map, edge_off, wsw + (size_t)i * 16384,
            b_e + i * DIM, g_e + i * DIM, be_e + i * DIM, (void*)exb, E);
        // E2N: pool fp8 edge rows per node (2xuint4 + lane^16 exchange), node-MLP
        fused_pool_gemm_ln_relu_v15_kernel<true, false><<<cdiv(N, 128), 512, 0, stream>>>(
            (const void*)exb, edges_map, node_off, wsw + (size_t)(2 + i) * 16384,
            b_n + i * DIM, g_n + i * DIM, be_n + i * DIM, (void*)xb, N);
        xcur = xb;
    }

    classifier_logsoftmax_v3_kernel<<<cdiv(N, 16 * CL_ROWS), 256, 0, stream>>>(
        (const uint4*)xcur, W_c, b_c, out, N);
}

// Round 15
// 307.510 us; speedup vs baseline: 1.2295x; 1.0016x over previous
//
#include <hip/hip_runtime.h>
#include <hip/hip_bf16.h>

#define DIM 128

typedef __bf16 bf16x8 __attribute__((ext_vector_type(8)));
typedef float f32x4 __attribute__((ext_vector_type(4)));
typedef float f32x2 __attribute__((ext_vector_type(2)));

static inline int cdiv(int a, int b) { return (a + b - 1) / b; }
static inline size_t align256(size_t x) { return (x + 255) & ~size_t(255); }

__device__ inline unsigned short f2bf(float f) {
    union { float f; unsigned int u; } v; v.f = f;
    unsigned int r = v.u + 0x7fff + ((v.u >> 16) & 1);   // RNE
    return (unsigned short)(r >> 16);
}
__device__ inline unsigned int hb(float f) {             // half-up bf16, 2 ops
    return (__builtin_bit_cast(unsigned int, f) + 0x8000u) >> 16;
}

// -------- setup (merged): segment offsets (both tables) + fp32->bf16 convert
// + W swizzle, one launch.
__global__ void setup_all_kernel(const int* __restrict__ segA, int mA, int nA,
                                 int* __restrict__ offA,
                                 const int* __restrict__ segB, int mB, int nB,
                                 int* __restrict__ offB,
                                 const float* __restrict__ xin,
                                 unsigned short* __restrict__ xout, int n4,
                                 const float* __restrict__ W_e,
                                 const float* __restrict__ W_n,
                                 unsigned short* __restrict__ wsw) {
    int gid = blockIdx.x * blockDim.x + threadIdx.x;

    // job B: fp32 -> bf16 convert (bulk of the work, n4 = N*DIM/4 threads)
    if (gid < n4) {
        float4 v = ((const float4*)xin)[gid];
        ushort4 o;
        o.x = f2bf(v.x); o.y = f2bf(v.y); o.z = f2bf(v.z); o.w = f2bf(v.w);
        ((ushort4*)xout)[gid] = o;
    }

    // job A: segment-offset tables via binary search
    if (gid <= nA) {
        int lo = 0, hi = mA;
        while (lo < hi) { int mid = (lo + hi) >> 1; if (segA[mid] < gid) lo = mid + 1; else hi = mid; }
        offA[gid] = lo;
    }
    int jj = gid - (nA + 1);
    if (jj >= 0 && jj <= nB) {
        int lo = 0, hi = mB;
        while (lo < hi) { int mid = (lo + hi) >> 1; if (segB[mid] < jj) lo = mid + 1; else hi = mid; }
        offB[jj] = lo;
    }

    // job C: pre-swizzle W (4 matrices of 128x128 fp32) into frag-major bf16
    if (gid < 8192) {
        int mi = gid >> 11;
        int e = gid & 2047;
        const float* W = (mi < 2) ? (W_e + (size_t)mi * DIM * DIM)
                                  : (W_n + (size_t)(mi - 2) * DIM * DIM);
        int t = e >> 9, n = (e >> 6) & 7, lane = e & 63;
        int q = lane >> 4, c = lane & 15;
        int k0 = t * 32 + q * 8, col = n * 16 + c;
        unsigned short vals[8];
#pragma unroll
        for (int j = 0; j < 8; ++j) vals[j] = f2bf(W[(size_t)(k0 + j) * DIM + col]);
        ushort4* dst = (ushort4*)(wsw + (size_t)gid * 8);
        dst[0] = make_ushort4(vals[0], vals[1], vals[2], vals[3]);
        dst[1] = make_ushort4(vals[4], vals[5], vals[6], vals[7]);
    }
}

// bf16 accumulate: 3 VALU/uint (hi = direct bitcast; validated since v7)
__device__ inline void accum8(float* a, uint4 v) {
    unsigned int u[4] = {v.x, v.y, v.z, v.w};
#pragma unroll
    for (int i = 0; i < 4; ++i) {
        a[2 * i]     += __builtin_bit_cast(float, u[i] << 16);
        a[2 * i + 1] += __builtin_bit_cast(float, u[i]);
    }
}
// fp8 e4m3 accumulate: uint4 = 16 bytes = 16 features -> 16 f32 adds
__device__ inline void accum16f8(float* a, uint4 v) {
    unsigned int u[4] = {v.x, v.y, v.z, v.w};
#pragma unroll
    for (int d = 0; d < 4; ++d) {
        f32x2 p0 = __builtin_amdgcn_cvt_pk_f32_fp8((int)u[d], false);
        f32x2 p1 = __builtin_amdgcn_cvt_pk_f32_fp8((int)u[d], true);
        a[4 * d + 0] += p0[0]; a[4 * d + 1] += p0[1];
        a[4 * d + 2] += p1[0]; a[4 * d + 3] += p1[1];
    }
}

// -------- kernel 4 v17: v15 (8-req fp8 gather / 16-req bf16 gather, W in LDS,
// single barrier) + CLASSIFIER FUSED into the final E2N epilogue (DO_CLS).
// R13 post-mortem: cooperative launch is rejected under graph capture, and
// boundary cost is only ~3us each — so fuse only where fusion also kills
// memory traffic: the final E2N's xb write (25MB) + classifier's xb read.
// Lane (q,c) holds cols {n*16+c} of its 4 rows; the 16 c-lanes of a q-group
// jointly hold the full row -> logits via the existing 16-lane shfl reduce.
// Classifier input re-rounded to bf16 in-register == v15's xb bytes.
template<bool IN8, bool OUT8, bool DO_CLS>
__global__ __launch_bounds__(512)
void fused_pool_gemm_ln_relu_v17_kernel(const void* __restrict__ src,
                                        const int* __restrict__ map,
                                        const int* __restrict__ off,
                                        const unsigned short* __restrict__ Wsw,
                                        const float* __restrict__ b,
                                        const float* __restrict__ g,
                                        const float* __restrict__ be,
                                        void* __restrict__ Y,
                                        int nseg,
                                        const float* __restrict__ Wc,
                                        const float* __restrict__ bc,
                                        float* __restrict__ out) {
    __shared__ bf16x8 wlds[2048];              // 32 KB frag-major W
    __shared__ float wclds[1290];              // 5.2 KB Wc+bc (DO_CLS only)
    int tid = threadIdx.x;
    int w = tid >> 6, lane = tid & 63;
    int q = lane >> 4, c = lane & 15;

    {   // stage swizzled W (global layout == LDS layout)
        const uint4* gsrc = (const uint4*)Wsw;
        uint4* ldst = (uint4*)wlds;
#pragma unroll
        for (int i = 0; i < 4; ++i) ldst[tid + i * 512] = gsrc[tid + i * 512];
    }
    if constexpr (DO_CLS) {
        for (int i = tid; i < 1290; i += 512)
            wclds[i] = (i < 1280) ? Wc[i] : bc[i - 1280];
    }

    int blockbase = blockIdx.x * 128;
    int seg = min(blockbase + w * 16 + c, nseg - 1);
    int beg = off[seg], end = off[seg + 1];
    int e1 = max(end - 1, 0);
    unsigned r = (unsigned)map[min(beg, e1)];   // first member, issued pre-barrier

    __syncthreads();   // only barrier: W (and Wc) visible to all waves

    const char* sbase = (const char*)src;
    float inv;
    bf16x8 af[4];

    if constexpr (!IN8) {
        // ---- bf16 rows (256 B): fragment-layout pooling, 16B/lane x4 (minimal)
        float a[4][8];
#pragma unroll
        for (int t = 0; t < 4; ++t)
#pragma unroll
            for (int i = 0; i < 8; ++i) a[t][i] = 0.f;

        unsigned qb = (unsigned)(q << 4);
        for (int j = beg; j < end; ++j) {
            const char* p = sbase + ((r << 8) + qb);
            uint4 v0 = *(const uint4*)(p);
            uint4 v1 = *(const uint4*)(p + 64);
            uint4 v2 = *(const uint4*)(p + 128);
            uint4 v3 = *(const uint4*)(p + 192);
            unsigned rn = (unsigned)map[min(j + 1, e1)];   // prefetch next index
            accum8(a[0], v0);
            accum8(a[1], v1);
            accum8(a[2], v2);
            accum8(a[3], v3);
            r = rn;
        }
        inv = 1.f / fmaxf((float)(end - beg), 1.f);
#pragma unroll
        for (int t = 0; t < 4; ++t) {
            uint4 o;
            o.x = hb(a[t][0] * inv) | (hb(a[t][1] * inv) << 16);
            o.y = hb(a[t][2] * inv) | (hb(a[t][3] * inv) << 16);
            o.z = hb(a[t][4] * inv) | (hb(a[t][5] * inv) << 16);
            o.w = hb(a[t][6] * inv) | (hb(a[t][7] * inv) << 16);
            af[t] = __builtin_bit_cast(bf16x8, o);
        }
    } else {
        // ---- fp8 rows (128 B): unit-layout pooling, 2 x uint4 per lane (8 req/row)
        float a0[16], a1[16];
#pragma unroll
        for (int i = 0; i < 16; ++i) { a0[i] = 0.f; a1[i] = 0.f; }

        unsigned qb = 16u * ((unsigned)(q >> 1) + 4u * (unsigned)(q & 1));
        for (int j = beg; j < end; ++j) {
            const char* p = sbase + ((r << 7) + qb);
            uint4 u0 = *(const uint4*)(p);
            uint4 u1 = *(const uint4*)(p + 32);
            unsigned rn = (unsigned)map[min(j + 1, e1)];   // prefetch next index
            accum16f8(a0, u0);
            accum16f8(a1, u1);
            r = rn;
        }
        inv = 1.f / fmaxf((float)(end - beg), 1.f);

        // mean + pack each unit to 8 dwords (16 bf16)
        unsigned pk0[8], pk1[8];
#pragma unroll
        for (int j = 0; j < 8; ++j) {
            pk0[j] = hb(a0[2 * j] * inv) | (hb(a0[2 * j + 1] * inv) << 16);
            pk1[j] = hb(a1[2 * j] * inv) | (hb(a1[2 * j + 1] * inv) << 16);
        }
        int h = q & 1;   // my half within each unit
        unsigned own0[4], own1[4], rec0[4], rec1[4];
#pragma unroll
        for (int k = 0; k < 4; ++k) {
            unsigned s0 = h ? pk0[k] : pk0[k + 4];
            unsigned s1 = h ? pk1[k] : pk1[k + 4];
            rec0[k] = (unsigned)__shfl_xor((int)s0, 16);
            rec1[k] = (unsigned)__shfl_xor((int)s1, 16);
            own0[k] = h ? pk0[k + 4] : pk0[k];
            own1[k] = h ? pk1[k + 4] : pk1[k];
        }
        unsigned f0[4], f1[4], f2[4], f3[4];
#pragma unroll
        for (int k = 0; k < 4; ++k) {
            f0[k] = h ? rec0[k] : own0[k];
            f1[k] = h ? rec1[k] : own1[k];
            f2[k] = h ? own0[k] : rec0[k];
            f3[k] = h ? own1[k] : rec1[k];
        }
        af[0] = __builtin_bit_cast(bf16x8, make_uint4(f0[0], f0[1], f0[2], f0[3]));
        af[1] = __builtin_bit_cast(bf16x8, make_uint4(f1[0], f1[1], f1[2], f1[3]));
        af[2] = __builtin_bit_cast(bf16x8, make_uint4(f2[0], f2[1], f2[2], f2[3]));
        af[3] = __builtin_bit_cast(bf16x8, make_uint4(f3[0], f3[1], f3[2], f3[3]));
    }

    // bias (seeds acc); g/be deferred past MFMA to cap pressure
    float bcol[8];
#pragma unroll
    for (int n = 0; n < 8; ++n) bcol[n] = b[n * 16 + c];

    f32x4 acc[8];
#pragma unroll
    for (int n = 0; n < 8; ++n) acc[n] = f32x4{bcol[n], bcol[n], bcol[n], bcol[n]};

    // ---- phase 2: GEMM from register A-fragments (no barrier needed)
#pragma unroll
    for (int n = 0; n < 8; ++n) {
        acc[n] = __builtin_amdgcn_mfma_f32_16x16x32_bf16(af[0], wlds[(0 * 8 + n) * 64 + lane], acc[n], 0, 0, 0);
        acc[n] = __builtin_amdgcn_mfma_f32_16x16x32_bf16(af[1], wlds[(1 * 8 + n) * 64 + lane], acc[n], 0, 0, 0);
        acc[n] = __builtin_amdgcn_mfma_f32_16x16x32_bf16(af[2], wlds[(2 * 8 + n) * 64 + lane], acc[n], 0, 0, 0);
        acc[n] = __builtin_amdgcn_mfma_f32_16x16x32_bf16(af[3], wlds[(3 * 8 + n) * 64 + lane], acc[n], 0, 0, 0);
    }

    // LN sums per row (lane's rows: blockbase + w*16 + q*4 + j, col n*16+c)
    float s1[4], s2[4];
#pragma unroll
    for (int j = 0; j < 4; ++j) {
        float t1 = 0.f, t2 = 0.f;
#pragma unroll
        for (int n = 0; n < 8; ++n) { float v = acc[n][j]; t1 += v; t2 = fmaf(v, v, t2); }
        s1[j] = t1; s2[j] = t2;
    }
#pragma unroll
    for (int o = 1; o < 16; o <<= 1)
#pragma unroll
        for (int j = 0; j < 4; ++j) {
            s1[j] += __shfl_xor(s1[j], o);
            s2[j] += __shfl_xor(s2[j], o);
        }

    float gcol[8], becol[8];
#pragma unroll
    for (int n = 0; n < 8; ++n) {
        int col = n * 16 + c;
        gcol[n] = g[col]; becol[n] = be[col];
    }

#pragma unroll
    for (int j = 0; j < 4; ++j) {
        int row = blockbase + w * 16 + q * 4 + j;
        if (row >= nseg) continue;
        float m = s1[j] * (1.f / DIM);
        float var = fmaf(-m, m, s2[j] * (1.f / DIM));
        float invs = rsqrtf(var + 1e-5f);
        if constexpr (DO_CLS) {
            // fused classifier: bf16-rounded y (== v15's stored xb bytes),
            // per-lane partial over its 8 cols, 16-lane shfl reduce, logsoftmax
            float cls[10];
#pragma unroll
            for (int cc = 0; cc < 10; ++cc) cls[cc] = 0.f;
#pragma unroll
            for (int n = 0; n < 8; ++n) {
                float d = acc[n][j] - m;
                float y = fmaxf(fmaf(d * invs, gcol[n], becol[n]), 0.f);
                unsigned int u = (__builtin_bit_cast(unsigned int, y) + 0x8000u) & 0xffff0000u;
                float yb = __builtin_bit_cast(float, u);
                const float* wr = &wclds[(n * 16 + c) * 10];
#pragma unroll
                for (int cc = 0; cc < 10; ++cc) cls[cc] = fmaf(yb, wr[cc], cls[cc]);
            }
#pragma unroll
            for (int o = 1; o < 16; o <<= 1)
#pragma unroll
                for (int cc = 0; cc < 10; ++cc) cls[cc] += __shfl_xor(cls[cc], o);
#pragma unroll
            for (int cc = 0; cc < 10; ++cc) cls[cc] += wclds[1280 + cc];

            float mx = cls[0];
#pragma unroll
            for (int cc = 1; cc < 10; ++cc) mx = fmaxf(mx, cls[cc]);
            float se = 0.f;
#pragma unroll
            for (int cc = 0; cc < 10; ++cc) se += expf(cls[cc] - mx);
            float lse = mx + logf(se);

            float myv = 0.f;
#pragma unroll
            for (int cc = 0; cc < 10; ++cc) myv = (c == cc) ? cls[cc] : myv;
            if (c < 10) out[(size_t)row * 10 + c] = myv - lse;
        } else if constexpr (!OUT8) {
            unsigned short* yp = (unsigned short*)Y + (size_t)row * DIM + c;
#pragma unroll
            for (int n = 0; n < 8; ++n) {
                float d = acc[n][j] - m;
                float y = fmaxf(fmaf(d * invs, gcol[n], becol[n]), 0.f);
                unsigned int u = __builtin_bit_cast(unsigned int, y) + 0x8000u;  // half-up
                yp[n * 16] = (unsigned short)(u >> 16);
            }
        } else {
            unsigned char* yp = (unsigned char*)Y + (size_t)row * DIM + c;
#pragma unroll
            for (int n = 0; n < 8; ++n) {
                float d = acc[n][j] - m;
                float y = fmaxf(fmaf(d * invs, gcol[n], becol[n]), 0.f);
                int e = __builtin_amdgcn_cvt_pk_fp8_f32(y, y, 0, false);
                yp[n * 16] = (unsigned char)e;
            }
        }
    }
}

extern "C" void kernel_launch(void* const* d_in, const int* in_sizes, int n_in,
                              void* d_out, int out_size, void* d_ws, size_t ws_size,
                              hipStream_t stream) {
    const float* node_x    = (const float*)d_in[0];
    const int*   nodes_map = (const int*)d_in[1];
    const int*   edge_seg  = (const int*)d_in[2];
    const int*   edges_map = (const int*)d_in[3];
    const int*   node_seg  = (const int*)d_in[4];
    const float* W_e = (const float*)d_in[6];
    const float* b_e = (const float*)d_in[7];
    const float* g_e = (const float*)d_in[8];
    const float* be_e= (const float*)d_in[9];
    const float* W_n = (const float*)d_in[10];
    const float* b_n = (const float*)d_in[11];
    const float* g_n = (const float*)d_in[12];
    const float* be_n= (const float*)d_in[13];
    const float* W_c = (const float*)d_in[14];
    const float* b_c = (const float*)d_in[15];
    float* out = (float*)d_out;

    const int N = in_sizes[0] / DIM;           // 100000
    const int M = in_sizes[1];                 // 800000
    const int E = 200000;                      // N_EDGES (problem constant)
    const int L = in_sizes[6] / (DIM * DIM);   // 2

    // workspace carve-up (exb fp8: E*128 bytes)
    char* ws = (char*)d_ws;
    int* edge_off = (int*)ws;           ws += align256((size_t)(E + 1) * sizeof(int));
    int* node_off = (int*)ws;           ws += align256((size_t)(N + 1) * sizeof(int));
    unsigned short* wsw = (unsigned short*)ws;      ws += align256((size_t)4 * 2048 * 8 * sizeof(unsigned short));
    unsigned short* node_xb = (unsigned short*)ws;  ws += align256((size_t)N * DIM * sizeof(unsigned short));
    unsigned char* exb = (unsigned char*)ws;        ws += align256((size_t)E * DIM);
    unsigned short* xb  = (unsigned short*)ws;      ws += align256((size_t)N * DIM * sizeof(unsigned short));
    (void)ws_size;

    setup_all_kernel<<<cdiv(N * DIM / 4, 256), 256, 0, stream>>>(
        edge_seg, M, E, edge_off, node_seg, M, N, node_off,
        node_x, node_xb, N * DIM / 4, W_e, W_n, wsw);

    const unsigned short* xcur = node_xb;
    for (int i = 0; i < L; ++i) {
        // N2E: pool bf16 node rows per hyperedge, edge-MLP, write fp8 edge rows
        fused_pool_gemm_ln_relu_v17_kernel<false, true, false><<<cdiv(E, 128), 512, 0, stream>>>(
            (const void*)xcur, nodes_map, edge_off, wsw + (size_t)i * 16384,
            b_e + i * DIM, g_e + i * DIM, be_e + i * DIM, (void*)exb, E,
            nullptr, nullptr, nullptr);
        if (i < L - 1) {
            // E2N: pool fp8 edge rows per node (8 req/row), node-MLP, bf16 out
            fused_pool_gemm_ln_relu_v17_kernel<true, false, false><<<cdiv(N, 128), 512, 0, stream>>>(
                (const void*)exb, edges_map, node_off, wsw + (size_t)(2 + i) * 16384,
                b_n + i * DIM, g_n + i * DIM, be_n + i * DIM, (void*)xb, N,
                nullptr, nullptr, nullptr);
            xcur = xb;
        } else {
            // final E2N: node-MLP + FUSED classifier+log_softmax (no xb write)
            fused_pool_gemm_ln_relu_v17_kernel<true, false, true><<<cdiv(N, 128), 512, 0, stream>>>(
                (const void*)exb, edges_map, node_off, wsw + (size_t)(2 + i) * 16384,
                b_n + i * DIM, g_n + i * DIM, be_n + i * DIM, (void*)xb, N,
                W_c, b_c, out);
        }
    }
}